// Round 3
// baseline (15138.091 us; speedup 1.0000x reference)
//
#include <hip/hip_runtime.h>

// LSTM char-RNN scan: B=512, SEQ=1024, UNITS=256, NUM_CHARS=128. ALL FP32.
// (Round-2 fix: inputs/outputs are fp32, not bf16 — round-1 read fp32 bits
// as bf16 pairs, producing NaN weights with P=1/256 per element.)
//
// Strategy: batch-parallel persistent workgroups. 256 WGs (1/CU), each owns
// BC=2 batch rows and runs the full 1024-step scan independently.
// Per step: stream W_h (fp32, 1 MB) from per-XCD L2, fp32 FMA into
// per-thread gate accumulators, exchange gates through LDS, elementwise
// LSTM update. Expected bound: per-CU L2 BW (~56 B/cyc) -> ~7.8 us/step.

#define B_TOT   512
#define SEQ     1024
#define U       256
#define NC      128
#define GDIM    1024      // 4*U
#define BC      2         // batch rows per workgroup
#define THREADS 512       // 8 waves

__device__ __forceinline__ float sig_(float x) {
    return 1.0f / (1.0f + __expf(-x));
}

__device__ __forceinline__ float tanh_(float x) {
    // 1 - 2/(e^{2x}+1): saturates correctly at +-1, no NaN
    return 1.0f - 2.0f / (__expf(2.0f * x) + 1.0f);
}

__global__ __launch_bounds__(THREADS)
void lstm_scan_kernel(const int* __restrict__ tokens,
                      const float* __restrict__ Wx,   // [128,1024]
                      const float* __restrict__ Wh,   // [256,1024]
                      const float* __restrict__ bias, // [1024]
                      const float* __restrict__ Wd,   // [256,128]
                      const float* __restrict__ bd,   // [128]
                      float* __restrict__ out)        // [512,128]
{
    __shared__ float h_lds[BC][U];     // 2 KB fp32 hidden state
    __shared__ float G[BC][GDIM];      // 8 KB fp32 gates
    __shared__ int   tok[BC * SEQ];    // 8 KB this WG's tokens

    const int tid = threadIdx.x;
    const int r0  = blockIdx.x * BC;   // first batch row of this WG

    // Preload tokens for our rows (contiguous: rows r0, r0+1)
    for (int i = tid; i < BC * SEQ; i += THREADS)
        tok[i] = tokens[r0 * SEQ + i];

    // Init hidden state
    h_lds[tid >> 8][tid & 255] = 0.0f;

    // Each thread owns 2 gate columns (col0, col0+1) for both rows,
    // and owns LSTM cell (r = tid>>8, u = tid&255) in the update phase.
    const int col0 = tid * 2;
    const float2 b2 = *(const float2*)(bias + col0);
    float c_state = 0.0f;              // cell state for (tid>>8, tid&255)
    const int ur = tid >> 8;           // update-phase row
    const int uu = tid & 255;          // update-phase unit

    __syncthreads();

    for (int t = 0; t < SEQ; ++t) {
        const int x0 = tok[t];
        const int x1 = tok[SEQ + t];

        // acc[row][j] for j in {0,1}: init with W_x[x_t] + b
        float2 wx0 = *(const float2*)(Wx + x0 * GDIM + col0);
        float2 wx1 = *(const float2*)(Wx + x1 * GDIM + col0);
        float a00 = wx0.x + b2.x, a01 = wx0.y + b2.y;
        float a10 = wx1.x + b2.x, a11 = wx1.y + b2.y;

        // GEMM phase: acc += h[r][k] * W_h[k][col]
        const float* wp = Wh + col0;
        #pragma unroll 8
        for (int k = 0; k < U; ++k) {
            float2 w = *(const float2*)(wp + k * GDIM);
            float h0 = h_lds[0][k];
            float h1 = h_lds[1][k];
            a00 = fmaf(h0, w.x, a00); a01 = fmaf(h0, w.y, a01);
            a10 = fmaf(h1, w.x, a10); a11 = fmaf(h1, w.y, a11);
        }

        // Publish gates
        *(float2*)&G[0][col0] = make_float2(a00, a01);
        *(float2*)&G[1][col0] = make_float2(a10, a11);
        __syncthreads();

        // LSTM elementwise update for cell (ur, uu). Gate order: i, j, f, o.
        {
            float gi = G[ur][uu];
            float gj = G[ur][U + uu];
            float gf = G[ur][2 * U + uu];
            float go = G[ur][3 * U + uu];
            c_state = c_state * sig_(gf + 1.0f) + sig_(gi) * tanh_(gj);
            float nh = tanh_(c_state) * sig_(go);
            __syncthreads();   // all G/h reads done before overwriting h
            h_lds[ur][uu] = nh;
        }
        __syncthreads();       // h visible for next step's GEMM
    }

    // Final dense: logits[r][n] = h[r][:] . W_dense[:,n] + b_dense[n]
    if (tid < BC * NC) {
        const int r = tid >> 7;       // 0..BC-1
        const int n = tid & (NC - 1); // 0..127
        float sum = bd[n];
        #pragma unroll 4
        for (int k = 0; k < U; ++k)
            sum = fmaf(h_lds[r][k], Wd[k * NC + n], sum);
        out[(r0 + r) * NC + n] = sum;
    }
}

extern "C" void kernel_launch(void* const* d_in, const int* in_sizes, int n_in,
                              void* d_out, int out_size, void* d_ws, size_t ws_size,
                              hipStream_t stream) {
    const int*   tokens = (const int*)d_in[0];
    const float* Wx     = (const float*)d_in[1];
    const float* Wh     = (const float*)d_in[2];
    const float* bias   = (const float*)d_in[3];
    const float* Wd     = (const float*)d_in[4];
    const float* bd     = (const float*)d_in[5];
    float*       out    = (float*)d_out;

    dim3 grid(B_TOT / BC);   // 256 workgroups, one per CU
    dim3 block(THREADS);     // 512 threads = 8 waves
    lstm_scan_kernel<<<grid, block, 0, stream>>>(tokens, Wx, Wh, bias, Wd, bd, out);
}

// Round 4
// 8580.846 us; speedup vs baseline: 1.7642x; 1.7642x over previous
//
#include <hip/hip_runtime.h>

// LSTM char-RNN scan: B=512, SEQ=1024, UNITS=256, NUM_CHARS=128. fp32 in/out.
// Round 3: (a) W_h converted once per call to bf16 in d_ws (halves the
// 1 MB/step/CU L2 streaming that bound round 2); (b) 1024 threads (16 waves,
// 4/SIMD vs 2/SIMD before); (c) h broadcast via ds_read_b128 (2 LDS instrs
// per 4 k-iters per wave vs 8 scalar ds_read_b32 — round 2's hidden 10 us/step
// LDS serialization); (d) k-dim split 4-way across threads, partials reduced
// through LDS once per step. h, c, accumulators all fp32; only W_h is bf16.

#define B_TOT   512
#define SEQ     1024
#define U       256
#define NC      128
#define GDIM    1024      // 4*U
#define BC      2         // batch rows per workgroup
#define THREADS 1024      // 16 waves
#define KSLICES 4
#define KCH     (U / KSLICES)   // 64 k per slice
// thread tid: ksl = tid>>8 (k-slice), cg = tid&255, cols [cg*4, cg*4+3]

__device__ __forceinline__ float sig_(float x) {
    return 1.0f / (1.0f + __expf(-x));
}
__device__ __forceinline__ float tanh_(float x) {
    return 1.0f - 2.0f / (__expf(2.0f * x) + 1.0f);   // saturating, no NaN
}

// fp32 -> bf16 round-to-nearest-even, packed conversion of W_h into workspace
__global__ __launch_bounds__(256)
void convert_wh(const float* __restrict__ Wh, unsigned short* __restrict__ Whb) {
    int i = blockIdx.x * 256 + threadIdx.x;          // [0, 262144)
    union { float f; unsigned u; } v; v.f = Wh[i];
    unsigned r = v.u + 0x7FFFu + ((v.u >> 16) & 1u);
    Whb[i] = (unsigned short)(r >> 16);
}

template<bool BF16W>
__global__ __launch_bounds__(THREADS, 4)
void lstm_scan(const int* __restrict__ tokens,
               const float* __restrict__ Wx,    // [128,1024]
               const float* __restrict__ Whf,   // [256,1024] fp32 (fallback)
               const unsigned short* __restrict__ Whb, // [256,1024] bf16 (ws)
               const float* __restrict__ bias,  // [1024]
               const float* __restrict__ Wd,    // [256,128]
               const float* __restrict__ bd,    // [128]
               float* __restrict__ out)         // [512,128]
{
    __shared__ float h_lds[BC][U];               // 2 KB
    __shared__ float G4[KSLICES][BC][GDIM];      // 32 KB partial gates
    __shared__ int   tok[BC * SEQ];              // 8 KB

    const int tid  = threadIdx.x;
    const int r0   = blockIdx.x * BC;
    const int ksl  = tid >> 8;                   // 0..3
    const int cg   = tid & 255;
    const int col0 = cg * 4;
    const int kb0  = ksl * KCH;

    for (int i = tid; i < BC * SEQ; i += THREADS)
        tok[i] = tokens[r0 * SEQ + i];
    if (tid < BC * U)
        ((float*)h_lds)[tid] = 0.0f;

    const float b_c = bias[tid];                 // bias for reduction col c=tid
    float c_state = 0.0f;                        // update-phase cell (tid<512)
    const int ur = (tid >> 8) & 1;               // update row (tid<512)
    const int uu = tid & 255;

    __syncthreads();

    for (int t = 0; t < SEQ; ++t) {
        // ---- GEMM phase: partial gates over k in [kb0, kb0+KCH) ----
        float a00 = 0.f, a01 = 0.f, a02 = 0.f, a03 = 0.f;
        float a10 = 0.f, a11 = 0.f, a12 = 0.f, a13 = 0.f;

        #pragma unroll 4
        for (int kc = 0; kc < KCH; kc += 4) {
            const int kb = kb0 + kc;
            float4 h0v = *(const float4*)&h_lds[0][kb];   // broadcast b128
            float4 h1v = *(const float4*)&h_lds[1][kb];
            #pragma unroll
            for (int j = 0; j < 4; ++j) {
                const int k = kb + j;
                float w0, w1, w2, w3;
                if (BF16W) {
                    uint2 w = *(const uint2*)(Whb + k * GDIM + col0);
                    w0 = __uint_as_float(w.x << 16);
                    w1 = __uint_as_float(w.x & 0xffff0000u);
                    w2 = __uint_as_float(w.y << 16);
                    w3 = __uint_as_float(w.y & 0xffff0000u);
                } else {
                    float4 w = *(const float4*)(Whf + k * GDIM + col0);
                    w0 = w.x; w1 = w.y; w2 = w.z; w3 = w.w;
                }
                const float h0 = (j == 0) ? h0v.x : (j == 1) ? h0v.y : (j == 2) ? h0v.z : h0v.w;
                const float h1 = (j == 0) ? h1v.x : (j == 1) ? h1v.y : (j == 2) ? h1v.z : h1v.w;
                a00 = fmaf(h0, w0, a00); a01 = fmaf(h0, w1, a01);
                a02 = fmaf(h0, w2, a02); a03 = fmaf(h0, w3, a03);
                a10 = fmaf(h1, w0, a10); a11 = fmaf(h1, w1, a11);
                a12 = fmaf(h1, w2, a12); a13 = fmaf(h1, w3, a13);
            }
        }
        *(float4*)&G4[ksl][0][col0] = make_float4(a00, a01, a02, a03);
        *(float4*)&G4[ksl][1][col0] = make_float4(a10, a11, a12, a13);
        __syncthreads();

        // ---- reduce partials + W_x[x_t] + b ; in-place into G4[0] ----
        {
            const int x0 = tok[t];
            const int x1 = tok[SEQ + t];
            const int c  = tid;
            float g0 = G4[0][0][c] + G4[1][0][c] + G4[2][0][c] + G4[3][0][c]
                     + Wx[x0 * GDIM + c] + b_c;
            float g1 = G4[0][1][c] + G4[1][1][c] + G4[2][1][c] + G4[3][1][c]
                     + Wx[x1 * GDIM + c] + b_c;
            G4[0][0][c] = g0;
            G4[0][1][c] = g1;
        }
        __syncthreads();

        // ---- LSTM update (gate order i, j, f, o; forget_bias = 1.0) ----
        if (tid < BC * U) {
            float gi = G4[0][ur][uu];
            float gj = G4[0][ur][U + uu];
            float gf = G4[0][ur][2 * U + uu];
            float go = G4[0][ur][3 * U + uu];
            c_state = c_state * sig_(gf + 1.0f) + sig_(gi) * tanh_(gj);
            h_lds[ur][uu] = tanh_(c_state) * sig_(go);
        }
        __syncthreads();
    }

    // ---- final dense ----
    if (tid < BC * NC) {
        const int r = tid >> 7;
        const int n = tid & (NC - 1);
        float sum = bd[n];
        #pragma unroll 4
        for (int k = 0; k < U; ++k)
            sum = fmaf(h_lds[r][k], Wd[k * NC + n], sum);
        out[(r0 + r) * NC + n] = sum;
    }
}

extern "C" void kernel_launch(void* const* d_in, const int* in_sizes, int n_in,
                              void* d_out, int out_size, void* d_ws, size_t ws_size,
                              hipStream_t stream) {
    const int*   tokens = (const int*)d_in[0];
    const float* Wx     = (const float*)d_in[1];
    const float* Wh     = (const float*)d_in[2];
    const float* bias   = (const float*)d_in[3];
    const float* Wd     = (const float*)d_in[4];
    const float* bd     = (const float*)d_in[5];
    float*       out    = (float*)d_out;

    const size_t wh_bytes = (size_t)U * GDIM * sizeof(unsigned short); // 512 KB
    if (ws_size >= wh_bytes) {
        unsigned short* Whb = (unsigned short*)d_ws;
        convert_wh<<<U * GDIM / 256, 256, 0, stream>>>(Wh, Whb);
        lstm_scan<true><<<B_TOT / BC, THREADS, 0, stream>>>(
            tokens, Wx, Wh, Whb, bias, Wd, bd, out);
    } else {
        lstm_scan<false><<<B_TOT / BC, THREADS, 0, stream>>>(
            tokens, Wx, Wh, (const unsigned short*)nullptr, bias, Wd, bd, out);
    }
}

// Round 5
// 7607.655 us; speedup vs baseline: 1.9898x; 1.1279x over previous
//
#include <hip/hip_runtime.h>

// LSTM char-RNN scan: B=512, SEQ=1024, UNITS=256, NUM_CHARS=128. fp32 in/out.
// Round 4: streaming structure, stripped to the VMEM floor.
//  - thread t owns gate-col t, FULL k=256 contraction, both batch rows
//    (no k-split -> no partial-gate reduction phase, 2 barriers/step not 3)
//  - convert kernel pre-transposes W_h to bf16 k-quads: uint4 = 8 k-consecutive
//    weights of one column -> one dwordx4 per 8 k, perfectly coalesced
//  - h broadcast from LDS via float4 (same-address broadcast = free)
//  - 4 independent FMA accumulator chains/thread
// Numerics: W_h bf16 (RNE), everything else fp32 (same as round 3, absmax 4.9e-4).
// Structural ceiling: 512 KB/step/CU from L2 at ~64 B/cyc = 3.4 us/step = 3.6 ms.

#define B_TOT   512
#define SEQ     1024
#define U       256
#define NC      128
#define GDIM    1024      // 4*U
#define BC      2
#define THREADS 1024      // 16 waves
#define KQ      32        // 256 k / 8 per quad-group

__device__ __forceinline__ float sig_(float x) {
    return 1.0f / (1.0f + __expf(-x));
}
__device__ __forceinline__ float tanh_(float x) {
    return 1.0f - 2.0f / (__expf(2.0f * x) + 1.0f);   // saturating, no NaN
}
__device__ __forceinline__ unsigned rne16(float f) {
    union { float f; unsigned u; } v; v.f = f;
    return (v.u + 0x7FFFu + ((v.u >> 16) & 1u)) >> 16;
}
__device__ __forceinline__ float u2f(unsigned u) {
    union { unsigned u; float f; } v; v.u = u;
    return v.f;
}

// Whb[kq*1024 + c] = uint4; dword j packs (W[8kq+2j][c] lo, W[8kq+2j+1][c] hi)
__global__ __launch_bounds__(256)
void convert_wh(const float* __restrict__ Wh, uint4* __restrict__ Whb) {
    int idx = blockIdx.x * 256 + threadIdx.x;   // [0, 32768)
    int kq  = idx >> 10;
    int c   = idx & 1023;
    const float* base = Wh + (size_t)(kq * 8) * GDIM + c;
    unsigned p0 = rne16(base[0 * GDIM]) | (rne16(base[1 * GDIM]) << 16);
    unsigned p1 = rne16(base[2 * GDIM]) | (rne16(base[3 * GDIM]) << 16);
    unsigned p2 = rne16(base[4 * GDIM]) | (rne16(base[5 * GDIM]) << 16);
    unsigned p3 = rne16(base[6 * GDIM]) | (rne16(base[7 * GDIM]) << 16);
    Whb[idx] = make_uint4(p0, p1, p2, p3);
}

template<bool PACKED>
__global__ __launch_bounds__(THREADS, 4)
void lstm_scan(const int* __restrict__ tokens,
               const float* __restrict__ Wx,    // [128,1024]
               const float* __restrict__ Whf,   // [256,1024] fp32 (fallback)
               const uint4* __restrict__ Whb,   // packed bf16 (ws)
               const float* __restrict__ bias,  // [1024]
               const float* __restrict__ Wd,    // [256,128]
               const float* __restrict__ bd,    // [128]
               float* __restrict__ out)         // [512,128]
{
    __shared__ float h32[BC][U];      // 2 KB
    __shared__ float G2[GDIM][BC];    // 8 KB, gate cols x rows
    __shared__ int   tok[BC][SEQ];    // 8 KB

    const int tid = threadIdx.x;      // == gate column c
    const int r0  = blockIdx.x * BC;

    for (int i = tid; i < BC * SEQ; i += THREADS)
        ((int*)tok)[i] = tokens[r0 * SEQ + i];
    if (tid < BC * U)
        ((float*)h32)[tid] = 0.0f;

    const float b_c = bias[tid];
    float c_state = 0.0f;             // cell state (update threads tid<512)
    const int ur = tid >> 8;          // update row (valid for tid<512)
    const int uu = tid & 255;

    __syncthreads();

    const uint4* wp = Whb + tid;      // column base, stride 1024 uint4 per kq
    const float* wf = Whf + tid;

    for (int t = 0; t < SEQ; ++t) {
        const int x0 = tok[0][t];
        const int x1 = tok[1][t];
        // 4 independent accumulator chains (even-k / odd-k per row)
        float a0e = Wx[x0 * GDIM + tid] + b_c;
        float a1e = Wx[x1 * GDIM + tid] + b_c;
        float a0o = 0.f, a1o = 0.f;

        #pragma unroll 4
        for (int kq = 0; kq < KQ; ++kq) {
            float4 h0a = *(const float4*)&h32[0][kq * 8];
            float4 h0b = *(const float4*)&h32[0][kq * 8 + 4];
            float4 h1a = *(const float4*)&h32[1][kq * 8];
            float4 h1b = *(const float4*)&h32[1][kq * 8 + 4];
            float we0, wo0, we1, wo1, we2, wo2, we3, wo3;
            if (PACKED) {
                uint4 w = wp[kq << 10];
                we0 = u2f(w.x << 16); wo0 = u2f(w.x & 0xffff0000u);
                we1 = u2f(w.y << 16); wo1 = u2f(w.y & 0xffff0000u);
                we2 = u2f(w.z << 16); wo2 = u2f(w.z & 0xffff0000u);
                we3 = u2f(w.w << 16); wo3 = u2f(w.w & 0xffff0000u);
            } else {
                we0 = wf[(kq * 8 + 0) * GDIM]; wo0 = wf[(kq * 8 + 1) * GDIM];
                we1 = wf[(kq * 8 + 2) * GDIM]; wo1 = wf[(kq * 8 + 3) * GDIM];
                we2 = wf[(kq * 8 + 4) * GDIM]; wo2 = wf[(kq * 8 + 5) * GDIM];
                we3 = wf[(kq * 8 + 6) * GDIM]; wo3 = wf[(kq * 8 + 7) * GDIM];
            }
            a0e = fmaf(h0a.x, we0, a0e); a0o = fmaf(h0a.y, wo0, a0o);
            a1e = fmaf(h1a.x, we0, a1e); a1o = fmaf(h1a.y, wo0, a1o);
            a0e = fmaf(h0a.z, we1, a0e); a0o = fmaf(h0a.w, wo1, a0o);
            a1e = fmaf(h1a.z, we1, a1e); a1o = fmaf(h1a.w, wo1, a1o);
            a0e = fmaf(h0b.x, we2, a0e); a0o = fmaf(h0b.y, wo2, a0o);
            a1e = fmaf(h1b.x, we2, a1e); a1o = fmaf(h1b.y, wo2, a1o);
            a0e = fmaf(h0b.z, we3, a0e); a0o = fmaf(h0b.w, wo3, a0o);
            a1e = fmaf(h1b.z, we3, a1e); a1o = fmaf(h1b.w, wo3, a1o);
        }

        *(float2*)&G2[tid][0] = make_float2(a0e + a0o, a1e + a1o);
        __syncthreads();

        // LSTM update (gate order i, j, f, o; forget_bias = 1.0)
        if (tid < BC * U) {
            float gi = G2[uu][ur];
            float gj = G2[U + uu][ur];
            float gf = G2[2 * U + uu][ur];
            float go = G2[3 * U + uu][ur];
            c_state = c_state * sig_(gf + 1.0f) + sig_(gi) * tanh_(gj);
            h32[ur][uu] = tanh_(c_state) * sig_(go);
        }
        __syncthreads();
    }

    // final dense
    if (tid < BC * NC) {
        const int r = tid >> 7;
        const int n = tid & (NC - 1);
        float sum = bd[n];
        #pragma unroll 4
        for (int k = 0; k < U; ++k)
            sum = fmaf(h32[r][k], Wd[k * NC + n], sum);
        out[(r0 + r) * NC + n] = sum;
    }
}

extern "C" void kernel_launch(void* const* d_in, const int* in_sizes, int n_in,
                              void* d_out, int out_size, void* d_ws, size_t ws_size,
                              hipStream_t stream) {
    const int*   tokens = (const int*)d_in[0];
    const float* Wx     = (const float*)d_in[1];
    const float* Wh     = (const float*)d_in[2];
    const float* bias   = (const float*)d_in[3];
    const float* Wd     = (const float*)d_in[4];
    const float* bd     = (const float*)d_in[5];
    float*       out    = (float*)d_out;

    const size_t wh_bytes = (size_t)U * GDIM * sizeof(unsigned short); // 512 KB
    if (ws_size >= wh_bytes) {
        uint4* Whb = (uint4*)d_ws;
        convert_wh<<<(KQ * GDIM) / 256, 256, 0, stream>>>(Wh, Whb);
        lstm_scan<true><<<B_TOT / BC, THREADS, 0, stream>>>(
            tokens, Wx, Wh, Whb, bias, Wd, bd, out);
    } else {
        lstm_scan<false><<<B_TOT / BC, THREADS, 0, stream>>>(
            tokens, Wx, Wh, (const uint4*)nullptr, bias, Wd, bd, out);
    }
}